// Round 3
// baseline (136.497 us; speedup 1.0000x reference)
//
#include <hip/hip_runtime.h>
#include <math.h>

// Problem dims (fixed by setup_inputs)
#define BB 16
#define HH 64
#define WW 64
#define CC 512
#define CI 64
#define NROWS (BB * HH * WW)  // 65536 rows of length C
#define LN_EPS 1e-3f

typedef __attribute__((ext_vector_type(8))) short bf16x8;
typedef __attribute__((ext_vector_type(4))) float f32x4;

__device__ __forceinline__ unsigned short f2bf(float f) {
  union {
    float f;
    unsigned int u;
  } v;
  v.f = f;
  unsigned int r = v.u + 0x7FFF + ((v.u >> 16) & 1);  // RNE
  return (unsigned short)(r >> 16);
}

__device__ __forceinline__ float bf2f(unsigned short u) {
  union {
    unsigned int u;
    float f;
  } v;
  v.u = ((unsigned int)u) << 16;
  return v.f;
}

// ---------------------------------------------------------------------------
// Prep: transpose weights to k-contiguous bf16 so MFMA B-fragments are
// contiguous 16B loads. WcT[col][k]: col<64 -> Wf, col in [64,128) -> Wh.
// WoT[col][k]: col<512, k<64 from Wo[k][col].
// ---------------------------------------------------------------------------
__global__ __launch_bounds__(256) void sgsa_prep(
    const float* __restrict__ Wf, const float* __restrict__ Wh,
    const float* __restrict__ Wo, unsigned short* __restrict__ WcT,
    unsigned short* __restrict__ WoT) {
  int tid = blockIdx.x * 256 + threadIdx.x;
  for (int i = tid; i < 128 * 512; i += gridDim.x * 256) {
    int col = i >> 9, k = i & 511;
    float v = (col < 64) ? Wf[k * 64 + col] : Wh[k * 64 + (col - 64)];
    WcT[i] = f2bf(v);
  }
  for (int i = tid; i < 512 * 64; i += gridDim.x * 256) {
    int col = i >> 6, k = i & 63;
    WoT[i] = f2bf(Wo[k * 512 + col]);
  }
}

// ---------------------------------------------------------------------------
// K1 (MFMA): [fg|hl] = LN( x @ [Wf|Wh] ).  M=65536, N=128, K=512, bf16 MFMA
// with fp32 accumulate. One wave computes 32 rows x 128 cols.
// D layout (m89-verified): col = lane&15, row = (lane>>4)*4 + reg.
// ---------------------------------------------------------------------------
__global__ __launch_bounds__(256) void sgsa_k1_mfma(
    const float* __restrict__ x, const unsigned short* __restrict__ WcT,
    const float* __restrict__ gf, const float* __restrict__ bf,
    const float* __restrict__ gh, const float* __restrict__ bh,
    float* __restrict__ fg, float* __restrict__ hl) {
  const int lane = threadIdx.x & 63;
  const int wid = blockIdx.x * 4 + (threadIdx.x >> 6);
  const int row0 = wid * 32;
  const int cq = lane & 15;  // A-row-in-tile / B-col-in-tile / D-col
  const int kg = lane >> 4;  // k-group

  f32x4 acc[2][8];
#pragma unroll
  for (int rt = 0; rt < 2; ++rt)
#pragma unroll
    for (int ct = 0; ct < 8; ++ct) acc[rt][ct] = (f32x4){0.f, 0.f, 0.f, 0.f};

#pragma unroll 2
  for (int kk = 0; kk < 16; ++kk) {
    const int kb = kk * 32 + kg * 8;
    bf16x8 bfr[8];
#pragma unroll
    for (int ct = 0; ct < 8; ++ct) {
      const int col = ct * 16 + cq;
      bfr[ct] = *(const bf16x8*)&WcT[col * 512 + kb];
    }
#pragma unroll
    for (int rt = 0; rt < 2; ++rt) {
      const float* ap = &x[(size_t)(row0 + rt * 16 + cq) * CC + kb];
      f32x4 a0 = *(const f32x4*)ap;
      f32x4 a1 = *(const f32x4*)(ap + 4);
      bf16x8 af;
#pragma unroll
      for (int j = 0; j < 4; ++j) {
        af[j] = (short)f2bf(a0[j]);
        af[j + 4] = (short)f2bf(a1[j]);
      }
#pragma unroll
      for (int ct = 0; ct < 8; ++ct)
        acc[rt][ct] = __builtin_amdgcn_mfma_f32_16x16x32_bf16(
            af, bfr[ct], acc[rt][ct], 0, 0, 0);
    }
  }

  float gfv[4], bfv[4], ghv[4], bhv[4];
#pragma unroll
  for (int ct = 0; ct < 4; ++ct) {
    gfv[ct] = gf[ct * 16 + cq];
    bfv[ct] = bf[ct * 16 + cq];
    ghv[ct] = gh[ct * 16 + cq];
    bhv[ct] = bh[ct * 16 + cq];
  }

#pragma unroll
  for (int rt = 0; rt < 2; ++rt) {
#pragma unroll
    for (int r = 0; r < 4; ++r) {
      const int row = row0 + rt * 16 + kg * 4 + r;
      float s = acc[rt][0][r] + acc[rt][1][r] + acc[rt][2][r] + acc[rt][3][r];
      float q = acc[rt][0][r] * acc[rt][0][r] + acc[rt][1][r] * acc[rt][1][r] +
                acc[rt][2][r] * acc[rt][2][r] + acc[rt][3][r] * acc[rt][3][r];
#pragma unroll
      for (int m = 1; m < 16; m <<= 1) {
        s += __shfl_xor(s, m, 64);
        q += __shfl_xor(q, m, 64);
      }
      float mean = s * (1.f / 64.f);
      float var = q * (1.f / 64.f) - mean * mean;
      float inv = rsqrtf(var + LN_EPS);
#pragma unroll
      for (int ct = 0; ct < 4; ++ct) {
        float v = (acc[rt][ct][r] - mean) * inv * gfv[ct] + bfv[ct];
        fg[(size_t)row * CI + ct * 16 + cq] = v;
      }
      float s2 = acc[rt][4][r] + acc[rt][5][r] + acc[rt][6][r] + acc[rt][7][r];
      float q2 = acc[rt][4][r] * acc[rt][4][r] + acc[rt][5][r] * acc[rt][5][r] +
                 acc[rt][6][r] * acc[rt][6][r] + acc[rt][7][r] * acc[rt][7][r];
#pragma unroll
      for (int m = 1; m < 16; m <<= 1) {
        s2 += __shfl_xor(s2, m, 64);
        q2 += __shfl_xor(q2, m, 64);
      }
      float mean2 = s2 * (1.f / 64.f);
      float var2 = q2 * (1.f / 64.f) - mean2 * mean2;
      float inv2 = rsqrtf(var2 + LN_EPS);
#pragma unroll
      for (int ct = 0; ct < 4; ++ct) {
        float v = (acc[rt][ct + 4][r] - mean2) * inv2 * ghv[ct] + bhv[ct];
        hl[(size_t)row * CI + ct * 16 + cq] = v;
      }
    }
  }
}

// ---------------------------------------------------------------------------
// K23 fused: per (b,w) block, compute attn = softmax_h(f*g), t = attn*hl
// (kept in LDS as split hi/lo bf16), then out = LN_C(t @ Wo)*scale + x.
// Phase A: thread (q,d) owns 16 h values.  Phase B: wave wv owns 128 cols.
// t LDS layout [64][72] bf16 (pad 8 -> row stride 144B, 2-way bank alias max).
// ---------------------------------------------------------------------------
__global__ __launch_bounds__(256) void sgsa_k23(
    const float* __restrict__ fg, const float* __restrict__ hl,
    const unsigned short* __restrict__ WoT, const float* __restrict__ go,
    const float* __restrict__ bo, const float* __restrict__ scale,
    const float* __restrict__ x, float* __restrict__ out) {
  const int b = blockIdx.x >> 6;
  const int w = blockIdx.x & 63;
  const int tid = threadIdx.x;

  __shared__ unsigned short t_hi[64 * 72];
  __shared__ unsigned short t_lo[64 * 72];
  __shared__ float red[4][64];
  __shared__ float s_red[4][64];
  __shared__ float q_red[4][64];

  // ---------------- Phase A: softmax over h, build t in LDS ----------------
  {
    const int d = tid & 63;
    const int q = tid >> 6;  // 0..3, each owns 16 h values
    const size_t base_g = (size_t)((b * 64) * 64 + w) * 64;  // + h*4096
    const size_t base_f = (size_t)((b * 64 + w) * 64) * 64;  // + h*64

    float sv[16], hv[16];
#pragma unroll
    for (int i = 0; i < 16; ++i) {
      int h = q * 16 + i;
      float g = fg[base_g + (size_t)h * 4096 + d];
      float f = fg[base_f + (size_t)h * 64 + d];
      sv[i] = f * g;
      hv[i] = hl[base_g + (size_t)h * 4096 + d];
    }

    float m = sv[0];
#pragma unroll
    for (int i = 1; i < 16; ++i) m = fmaxf(m, sv[i]);
    red[q][d] = m;
    __syncthreads();
    m = fmaxf(fmaxf(red[0][d], red[1][d]), fmaxf(red[2][d], red[3][d]));
    __syncthreads();

    float ssum = 0.f;
#pragma unroll
    for (int i = 0; i < 16; ++i) {
      sv[i] = __expf(sv[i] - m);
      ssum += sv[i];
    }
    red[q][d] = ssum;
    __syncthreads();
    ssum = (red[0][d] + red[1][d]) + (red[2][d] + red[3][d]);
    float rinv = 1.f / ssum;

#pragma unroll
    for (int i = 0; i < 16; ++i) {
      int h = q * 16 + i;
      float t = sv[i] * rinv * hv[i];
      unsigned short th = f2bf(t);
      t_hi[h * 72 + d] = th;
      t_lo[h * 72 + d] = f2bf(t - bf2f(th));
    }
  }
  __syncthreads();

  // ---------------- Phase B: t @ Wo, LN over C, residual -------------------
  const int lane = tid & 63;
  const int wv = tid >> 6;
  const int col0 = wv * 128;
  const int cq = lane & 15;
  const int kg = lane >> 4;

  f32x4 acc[4][8];
#pragma unroll
  for (int rt = 0; rt < 4; ++rt)
#pragma unroll
    for (int ct = 0; ct < 8; ++ct) acc[rt][ct] = (f32x4){0.f, 0.f, 0.f, 0.f};

#pragma unroll
  for (int kk = 0; kk < 2; ++kk) {
    const int kb = kk * 32 + kg * 8;
    bf16x8 bfr[8];
#pragma unroll
    for (int ct = 0; ct < 8; ++ct) {
      const int col = col0 + ct * 16 + cq;
      bfr[ct] = *(const bf16x8*)&WoT[col * CI + kb];
    }
#pragma unroll
    for (int rt = 0; rt < 4; ++rt) {
      bf16x8 ah = *(const bf16x8*)&t_hi[(rt * 16 + cq) * 72 + kb];
      bf16x8 al = *(const bf16x8*)&t_lo[(rt * 16 + cq) * 72 + kb];
#pragma unroll
      for (int ct = 0; ct < 8; ++ct) {
        acc[rt][ct] = __builtin_amdgcn_mfma_f32_16x16x32_bf16(
            ah, bfr[ct], acc[rt][ct], 0, 0, 0);
        acc[rt][ct] = __builtin_amdgcn_mfma_f32_16x16x32_bf16(
            al, bfr[ct], acc[rt][ct], 0, 0, 0);
      }
    }
  }

  // per-row partial sums -> LDS -> cross-wave combine
#pragma unroll
  for (int rt = 0; rt < 4; ++rt) {
#pragma unroll
    for (int r = 0; r < 4; ++r) {
      float s = 0.f, qq = 0.f;
#pragma unroll
      for (int ct = 0; ct < 8; ++ct) {
        float v = acc[rt][ct][r];
        s += v;
        qq += v * v;
      }
#pragma unroll
      for (int m = 1; m < 16; m <<= 1) {
        s += __shfl_xor(s, m, 64);
        qq += __shfl_xor(qq, m, 64);
      }
      if (cq == 0) {
        s_red[wv][rt * 16 + kg * 4 + r] = s;
        q_red[wv][rt * 16 + kg * 4 + r] = qq;
      }
    }
  }
  __syncthreads();

  const float sc = scale[0];
  float gov[8], bov[8];
#pragma unroll
  for (int ct = 0; ct < 8; ++ct) {
    gov[ct] = go[col0 + ct * 16 + cq];
    bov[ct] = bo[col0 + ct * 16 + cq];
  }

#pragma unroll
  for (int rt = 0; rt < 4; ++rt) {
#pragma unroll
    for (int r = 0; r < 4; ++r) {
      const int h = rt * 16 + kg * 4 + r;  // row within tile == h
      float s = (s_red[0][h] + s_red[1][h]) + (s_red[2][h] + s_red[3][h]);
      float q = (q_red[0][h] + q_red[1][h]) + (q_red[2][h] + q_red[3][h]);
      float mean = s * (1.f / 512.f);
      float var = q * (1.f / 512.f) - mean * mean;
      float inv = rsqrtf(var + LN_EPS);
      const size_t base = (size_t)((b * 64 + h) * 64 + w) * CC;
#pragma unroll
      for (int ct = 0; ct < 8; ++ct) {
        const int col = col0 + ct * 16 + cq;
        float o = (acc[rt][ct][r] - mean) * inv * gov[ct] + bov[ct];
        out[base + col] = o * sc + x[base + col];
      }
    }
  }
}

// ---------------------------------------------------------------------------
extern "C" void kernel_launch(void* const* d_in, const int* in_sizes, int n_in,
                              void* d_out, int out_size, void* d_ws,
                              size_t ws_size, hipStream_t stream) {
  const float* x = (const float*)d_in[0];
  const float* Wf = (const float*)d_in[1];
  const float* Wh = (const float*)d_in[2];
  const float* Wo = (const float*)d_in[3];
  const float* gf = (const float*)d_in[4];
  const float* bf = (const float*)d_in[5];
  const float* gh = (const float*)d_in[6];
  const float* bh = (const float*)d_in[7];
  const float* go = (const float*)d_in[8];
  const float* bo = (const float*)d_in[9];
  const float* sc = (const float*)d_in[10];
  float* out = (float*)d_out;

  unsigned short* WcT = (unsigned short*)d_ws;      // 128*512*2 = 128 KiB
  unsigned short* WoT = WcT + 128 * 512;            // 512*64*2  =  64 KiB
  float* fg = (float*)((char*)d_ws + (256 << 10));  // 16 MiB
  float* hl = fg + (size_t)NROWS * CI;              // 16 MiB

  sgsa_prep<<<128, 256, 0, stream>>>(Wf, Wh, Wo, WcT, WoT);
  sgsa_k1_mfma<<<NROWS / 128, 256, 0, stream>>>(x, WcT, gf, bf, gh, bh, fg,
                                                hl);
  sgsa_k23<<<BB * WW, 256, 0, stream>>>(fg, hl, WoT, go, bo, sc, x, out);
}